// Round 5
// baseline (211.316 us; speedup 1.0000x reference)
//
#include <hip/hip_runtime.h>
#include <hip/hip_bf16.h>

#define NN 8192
#define IND 512
#define OUTD 64
#define ALPHA_ 0.2f
#define LOG2E 1.4426950408889634f

typedef float f32x4 __attribute__((ext_vector_type(4)));
typedef short s16x8 __attribute__((ext_vector_type(8)));
typedef int   i32x4 __attribute__((ext_vector_type(4)));
typedef unsigned int uint;
typedef unsigned long long ull;
typedef ull ullx2 __attribute__((ext_vector_type(2)));

static __device__ __forceinline__ short f2bf(float x) {
    __hip_bfloat16 b = __float2bfloat16(x);
    return *reinterpret_cast<short*>(&b);
}
// monotone float<->uint encode for atomicMax over floats
static __device__ __forceinline__ uint fenc(float f) {
    uint u = __float_as_uint(f);
    return (u & 0x80000000u) ? ~u : (u | 0x80000000u);
}
static __device__ __forceinline__ float fdec(uint k) {
    uint u = (k & 0x80000000u) ? (k & 0x7FFFFFFFu) : ~k;
    return __uint_as_float(u);
}

// ---- kernel 0: compress adj (int 0/1) to bitmask. Coalesced 1KB/inst reads. ----
// mask[row] = 128 u64. Chunk c (256 j): u64 index 4c+e holds ballot bits:
//   bit l of mask[row][4c+e]  =  (adj[row][c*256 + 4*l + e] != 0)
__global__ __launch_bounds__(256) void k_pack(const int* __restrict__ adj,
                                              ull* __restrict__ mask) {
    int tid = threadIdx.x;
    int w = tid >> 6, l = tid & 63;
    int row = blockIdx.x * 4 + w;
    const int* ap = adj + (size_t)row * NN + 4 * l;
    ull* mp = mask + (size_t)row * 128;

    for (int g = 0; g < 4; ++g) {          // 4 groups x 8 chunks x 1KB = 32KB row
        i32x4 v[8];
        #pragma unroll
        for (int k = 0; k < 8; ++k)
            v[k] = *(const i32x4*)(ap + (g * 8 + k) * 256);
        #pragma unroll
        for (int k = 0; k < 8; ++k) {
            ull b0 = __ballot(v[k][0] != 0);
            ull b1 = __ballot(v[k][1] != 0);
            ull b2 = __ballot(v[k][2] != 0);
            ull b3 = __ballot(v[k][3] != 0);
            if (l == 0) {
                ullx2 p0; p0[0] = b0; p0[1] = b1;
                ullx2 p1; p1[0] = b2; p1[1] = b3;
                *(ullx2*)(mp + (size_t)(g * 8 + k) * 4)     = p0;
                *(ullx2*)(mp + (size_t)(g * 8 + k) * 4 + 2) = p1;
            }
        }
    }
}

// ---- kernel 1: Wh = h@W; whT bf16 [64][8192]; Wh1s/Wh2s prescaled by log2e; atomic max ----
__global__ __launch_bounds__(256) void k_wh(const float* __restrict__ h,
                                            const float* __restrict__ W,
                                            const float* __restrict__ a,
                                            __hip_bfloat16* __restrict__ whT,
                                            float* __restrict__ Wh1s,
                                            float* __restrict__ Wh2s,
                                            uint* __restrict__ mxk) {
    __shared__ float hs[8 * IND];      // 16 KB
    int tid = threadIdx.x;
    const f32x4* h4 = (const f32x4*)(h + (size_t)blockIdx.x * 8 * IND);
    f32x4* hs4 = (f32x4*)hs;
    #pragma unroll
    for (int t = 0; t < 4; ++t) hs4[tid + t * 256] = h4[tid + t * 256];
    __syncthreads();

    int w = tid >> 6, l = tid & 63;
    int g = l >> 4, lc = l & 15;
    int c4 = lc * 4;
    const float* hrow = hs + (w * 2) * IND;
    f32x4 acc0 = {0.f, 0.f, 0.f, 0.f};
    f32x4 acc1 = {0.f, 0.f, 0.f, 0.f};

    #pragma unroll 4
    for (int k0 = 0; k0 < 128; ++k0) {
        int k = k0 * 4 + g;
        f32x4 wv = *(const f32x4*)(W + k * OUTD + c4);
        float h0 = hrow[k];
        float h1 = hrow[IND + k];
        acc0[0] = fmaf(h0, wv[0], acc0[0]);
        acc0[1] = fmaf(h0, wv[1], acc0[1]);
        acc0[2] = fmaf(h0, wv[2], acc0[2]);
        acc0[3] = fmaf(h0, wv[3], acc0[3]);
        acc1[0] = fmaf(h1, wv[0], acc1[0]);
        acc1[1] = fmaf(h1, wv[1], acc1[1]);
        acc1[2] = fmaf(h1, wv[2], acc1[2]);
        acc1[3] = fmaf(h1, wv[3], acc1[3]);
    }

    #pragma unroll
    for (int e = 0; e < 4; ++e) {
        acc0[e] += __shfl_xor(acc0[e], 16, 64);
        acc0[e] += __shfl_xor(acc0[e], 32, 64);
        acc1[e] += __shfl_xor(acc1[e], 16, 64);
        acc1[e] += __shfl_xor(acc1[e], 32, 64);
    }

    int row0 = blockIdx.x * 8 + w * 2;
    if (g == 0) {
        #pragma unroll
        for (int e = 0; e < 4; ++e) {
            whT[(size_t)(c4 + e) * NN + row0]     = __float2bfloat16(acc0[e]);
            whT[(size_t)(c4 + e) * NN + row0 + 1] = __float2bfloat16(acc1[e]);
        }
    }

    float p10 = 0.f, p20 = 0.f, p11 = 0.f, p21 = 0.f;
    #pragma unroll
    for (int e = 0; e < 4; ++e) {
        float a1 = a[c4 + e], a2 = a[OUTD + c4 + e];
        p10 = fmaf(acc0[e], a1, p10);
        p20 = fmaf(acc0[e], a2, p20);
        p11 = fmaf(acc1[e], a1, p11);
        p21 = fmaf(acc1[e], a2, p21);
    }
    #pragma unroll
    for (int off = 1; off < 16; off <<= 1) {
        p10 += __shfl_xor(p10, off, 64);
        p20 += __shfl_xor(p20, off, 64);
        p11 += __shfl_xor(p11, off, 64);
        p21 += __shfl_xor(p21, off, 64);
    }
    if (l == 0) {
        float s20 = p20 * LOG2E, s21 = p21 * LOG2E;
        Wh1s[row0]     = p10 * LOG2E;  Wh2s[row0]     = s20;
        Wh1s[row0 + 1] = p11 * LOG2E;  Wh2s[row0 + 1] = s21;
        atomicMax(mxk, fenc(fmaxf(s20, s21)));
    }
}

// ---- kernel 2: fused mask+softmax+PV, adjacency from bitmask (L2/L3-resident) ----
__global__ __launch_bounds__(512) void k_gat(const ull* __restrict__ mask,
                                             const __hip_bfloat16* __restrict__ whT,
                                             const float* __restrict__ Wh1s,
                                             const float* __restrict__ Wh2s,
                                             const uint* __restrict__ mxk,
                                             float* __restrict__ out) {
    int tid = threadIdx.x;
    int w   = tid >> 6;        // wave 0..7
    int l   = tid & 63;
    int lr  = l & 15;          // A-row / B-col within 16-tile
    int grp = l >> 4;          // k-group (8 consecutive j per lane)
    int ib  = blockIdx.x * 16;
    int row = ib + lr;

    float wh1s = Wh1s[row];
    float t0 = wh1s + fdec(*mxk);          // upper bound (scaled domain; leakyrelu monotone)
    float mcs = fmaxf(t0, ALPHA_ * t0);

    f32x4 acc0 = {0.f, 0.f, 0.f, 0.f};
    f32x4 acc1 = acc0, acc2 = acc0, acc3 = acc0, acc4 = acc0;
    s16x8 bones;
    #pragma unroll
    for (int e = 0; e < 8; ++e) bones[e] = (short)0x3F80;   // bf16 1.0

    const ull* mrow = mask + (size_t)row * 128;
    const __hip_bfloat16* bp = whT + (size_t)lr * NN;
    int w0 = w * 32 + grp * 8;
    int shamt = 8 * w + 2 * grp;

#define LOADJ(IT, M01, M23, W20, W21, B0, B1, B2, B3)          \
    M01 = *(const ullx2*)(mrow + (IT) * 4);                    \
    M23 = *(const ullx2*)(mrow + (IT) * 4 + 2);                \
    {  int jl = (IT) * 256 + w0;                               \
       W20 = *(const f32x4*)(Wh2s + jl);                       \
       W21 = *(const f32x4*)(Wh2s + jl + 4);                   \
       B0  = *(const s16x8*)(bp + jl);                         \
       B1  = *(const s16x8*)(bp + (size_t)16 * NN + jl);       \
       B2  = *(const s16x8*)(bp + (size_t)32 * NN + jl);       \
       B3  = *(const s16x8*)(bp + (size_t)48 * NN + jl);  }

    ullx2 m01, m23;
    f32x4 w20, w21;
    s16x8 b0, b1, b2, b3;
    LOADJ(0, m01, m23, w20, w21, b0, b1, b2, b3)

    for (int it = 0; it < 32; ++it) {
        ullx2 nm01, nm23;
        f32x4 nw20, nw21;
        s16x8 nb0, nb1, nb2, nb3;
        if (it < 31) {
            LOADJ(it + 1, nm01, nm23, nw20, nw21, nb0, nb1, nb2, nb3)
        }

        uint s0 = (uint)(m01[0] >> shamt);
        uint s1 = (uint)(m01[1] >> shamt);
        uint s2 = (uint)(m23[0] >> shamt);
        uint s3 = (uint)(m23[1] >> shamt);

        s16x8 af;
        #pragma unroll
        for (int e = 0; e < 8; ++e) {
            float t = wh1s + ((e < 4) ? w20[e & 3] : w21[e & 3]);
            float x = fmaxf(t, ALPHA_ * t);            // leaky relu (scaled domain)
            float p = exp2f(x - mcs);
            uint sb = (e & 3) == 0 ? s0 : (e & 3) == 1 ? s1 : (e & 3) == 2 ? s2 : s3;
            p = (sb & (1u << (e >> 2))) ? p : 0.f;     // adjacency bit
            af[e] = f2bf(p);
        }
        acc0 = __builtin_amdgcn_mfma_f32_16x16x32_bf16(af, b0, acc0, 0, 0, 0);
        acc1 = __builtin_amdgcn_mfma_f32_16x16x32_bf16(af, b1, acc1, 0, 0, 0);
        acc2 = __builtin_amdgcn_mfma_f32_16x16x32_bf16(af, b2, acc2, 0, 0, 0);
        acc3 = __builtin_amdgcn_mfma_f32_16x16x32_bf16(af, b3, acc3, 0, 0, 0);
        acc4 = __builtin_amdgcn_mfma_f32_16x16x32_bf16(af, bones, acc4, 0, 0, 0); // row-sum

        if (it < 31) {
            m01 = nm01; m23 = nm23;
            w20 = nw20; w21 = nw21;
            b0 = nb0; b1 = nb1; b2 = nb2; b3 = nb3;
        }
    }
#undef LOADJ

    // cross-wave combine via LDS
    __shared__ float lacc[8][16][65];
    __shared__ float lls[8][16];
    #pragma unroll
    for (int reg = 0; reg < 4; ++reg) {
        int rr = grp * 4 + reg;            // C layout: row=(lane>>4)*4+reg, col=lane&15
        lacc[w][rr][lr]      = acc0[reg];
        lacc[w][rr][16 + lr] = acc1[reg];
        lacc[w][rr][32 + lr] = acc2[reg];
        lacc[w][rr][48 + lr] = acc3[reg];
    }
    if (lr == 0) {
        #pragma unroll
        for (int reg = 0; reg < 4; ++reg) lls[w][grp * 4 + reg] = acc4[reg];
    }
    __syncthreads();

    #pragma unroll
    for (int t = 0; t < 2; ++t) {
        int idx = tid + t * 512;           // 1024 outputs: 16 rows x 64 cols
        int rr = idx >> 6, c = idx & 63;
        float v = 0.f, ls = 0.f;
        #pragma unroll
        for (int ww = 0; ww < 8; ++ww) {
            v += lacc[ww][rr][c];
            ls += lls[ww][rr];
        }
        float hv = v / ls;
        out[(size_t)(ib + rr) * OUTD + c] = hv > 0.f ? hv : exp2f(hv * LOG2E) - 1.f;
    }
}

extern "C" void kernel_launch(void* const* d_in, const int* in_sizes, int n_in,
                              void* d_out, int out_size, void* d_ws, size_t ws_size,
                              hipStream_t stream) {
    const float* h   = (const float*)d_in[0];
    const int*   adj = (const int*)d_in[1];
    const float* W   = (const float*)d_in[2];
    const float* a   = (const float*)d_in[3];
    float* out = (float*)d_out;

    char* ws = (char*)d_ws;
    ull*             mask = (ull*)ws;                                // 8 MB
    __hip_bfloat16*  whT  = (__hip_bfloat16*)(ws + 8388608);         // 1 MB
    float*           Wh1s = (float*)(ws + 8388608 + 1048576);        // 32 KB
    float*           Wh2s = Wh1s + NN;                               // 32 KB
    uint*            mxk  = (uint*)(Wh2s + NN);                      // 4 B

    hipMemsetAsync(mxk, 0, 4, stream);     // encoded -inf identity
    k_pack<<<NN / 4, 256, 0, stream>>>(adj, mask);
    k_wh<<<NN / 8, 256, 0, stream>>>(h, W, a, whT, Wh1s, Wh2s, mxk);
    k_gat<<<NN / 16, 512, 0, stream>>>(mask, whT, Wh1s, Wh2s, mxk, out);
}

// Round 6
// 195.145 us; speedup vs baseline: 1.0829x; 1.0829x over previous
//
#include <hip/hip_runtime.h>
#include <hip/hip_bf16.h>

#define NN 8192
#define IND 512
#define OUTD 64
#define ALPHA_ 0.2f
#define LOG2E 1.4426950408889634f

typedef float f32x4 __attribute__((ext_vector_type(4)));
typedef short s16x8 __attribute__((ext_vector_type(8)));
typedef int   i32x4 __attribute__((ext_vector_type(4)));
typedef unsigned int uint;
typedef unsigned long long ull;
typedef ull ullx2 __attribute__((ext_vector_type(2)));

static __device__ __forceinline__ short f2bf(float x) {
    __hip_bfloat16 b = __float2bfloat16(x);
    return *reinterpret_cast<short*>(&b);
}
static __device__ __forceinline__ uint fenc(float f) {
    uint u = __float_as_uint(f);
    return (u & 0x80000000u) ? ~u : (u | 0x80000000u);
}
static __device__ __forceinline__ float fdec(uint k) {
    uint u = (k & 0x80000000u) ? (k & 0x7FFFFFFFu) : ~k;
    return __uint_as_float(u);
}

// ---- kernel 0: compress adj to transposed bitmask maskP[rb][cc][rl][4] ----
// ull at ((rb*32+cc)*16+rl)*4 + e ; bit l = (adj[rb*16+rl][cc*256 + 4*l + e] != 0)
__global__ __launch_bounds__(256) void k_pack(const int* __restrict__ adj,
                                              ull* __restrict__ maskP) {
    int tid = threadIdx.x;
    int w = tid >> 6, l = tid & 63;
    int row = blockIdx.x * 4 + w;
    const int* ap = adj + (size_t)row * NN + 4 * l;
    ull* mp = maskP + (size_t)(row >> 4) * 2048 + (size_t)(row & 15) * 4;  // + cc*64

    for (int g = 0; g < 4; ++g) {          // 4 groups x 8 chunks x 1KB
        i32x4 v[8];
        #pragma unroll
        for (int k = 0; k < 8; ++k)
            v[k] = *(const i32x4*)(ap + (g * 8 + k) * 256);
        #pragma unroll
        for (int k = 0; k < 8; ++k) {
            ull b0 = __ballot(v[k][0] != 0);
            ull b1 = __ballot(v[k][1] != 0);
            ull b2 = __ballot(v[k][2] != 0);
            ull b3 = __ballot(v[k][3] != 0);
            if (l == 0) {
                ullx2 p0; p0[0] = b0; p0[1] = b1;
                ullx2 p1; p1[0] = b2; p1[1] = b3;
                *(ullx2*)(mp + (size_t)(g * 8 + k) * 64)     = p0;
                *(ullx2*)(mp + (size_t)(g * 8 + k) * 64 + 2) = p1;
            }
        }
    }
}

// ---- kernel 1: Wh = h@W; whT bf16 [64][8192]; Wh1s/Wh2s prescaled by log2e; atomic max ----
__global__ __launch_bounds__(256) void k_wh(const float* __restrict__ h,
                                            const float* __restrict__ W,
                                            const float* __restrict__ a,
                                            __hip_bfloat16* __restrict__ whT,
                                            float* __restrict__ Wh1s,
                                            float* __restrict__ Wh2s,
                                            uint* __restrict__ mxk) {
    __shared__ float hs[8 * IND];      // 16 KB
    int tid = threadIdx.x;
    const f32x4* h4 = (const f32x4*)(h + (size_t)blockIdx.x * 8 * IND);
    f32x4* hs4 = (f32x4*)hs;
    #pragma unroll
    for (int t = 0; t < 4; ++t) hs4[tid + t * 256] = h4[tid + t * 256];
    __syncthreads();

    int w = tid >> 6, l = tid & 63;
    int g = l >> 4, lc = l & 15;
    int c4 = lc * 4;
    const float* hrow = hs + (w * 2) * IND;
    f32x4 acc0 = {0.f, 0.f, 0.f, 0.f};
    f32x4 acc1 = {0.f, 0.f, 0.f, 0.f};

    #pragma unroll 4
    for (int k0 = 0; k0 < 128; ++k0) {
        int k = k0 * 4 + g;
        f32x4 wv = *(const f32x4*)(W + k * OUTD + c4);
        float h0 = hrow[k];
        float h1 = hrow[IND + k];
        acc0[0] = fmaf(h0, wv[0], acc0[0]);
        acc0[1] = fmaf(h0, wv[1], acc0[1]);
        acc0[2] = fmaf(h0, wv[2], acc0[2]);
        acc0[3] = fmaf(h0, wv[3], acc0[3]);
        acc1[0] = fmaf(h1, wv[0], acc1[0]);
        acc1[1] = fmaf(h1, wv[1], acc1[1]);
        acc1[2] = fmaf(h1, wv[2], acc1[2]);
        acc1[3] = fmaf(h1, wv[3], acc1[3]);
    }

    #pragma unroll
    for (int e = 0; e < 4; ++e) {
        acc0[e] += __shfl_xor(acc0[e], 16, 64);
        acc0[e] += __shfl_xor(acc0[e], 32, 64);
        acc1[e] += __shfl_xor(acc1[e], 16, 64);
        acc1[e] += __shfl_xor(acc1[e], 32, 64);
    }

    int row0 = blockIdx.x * 8 + w * 2;
    if (g == 0) {
        #pragma unroll
        for (int e = 0; e < 4; ++e) {
            whT[(size_t)(c4 + e) * NN + row0]     = __float2bfloat16(acc0[e]);
            whT[(size_t)(c4 + e) * NN + row0 + 1] = __float2bfloat16(acc1[e]);
        }
    }

    float p10 = 0.f, p20 = 0.f, p11 = 0.f, p21 = 0.f;
    #pragma unroll
    for (int e = 0; e < 4; ++e) {
        float a1 = a[c4 + e], a2 = a[OUTD + c4 + e];
        p10 = fmaf(acc0[e], a1, p10);
        p20 = fmaf(acc0[e], a2, p20);
        p11 = fmaf(acc1[e], a1, p11);
        p21 = fmaf(acc1[e], a2, p21);
    }
    #pragma unroll
    for (int off = 1; off < 16; off <<= 1) {
        p10 += __shfl_xor(p10, off, 64);
        p20 += __shfl_xor(p20, off, 64);
        p11 += __shfl_xor(p11, off, 64);
        p21 += __shfl_xor(p21, off, 64);
    }
    if (l == 0) {
        float s20 = p20 * LOG2E, s21 = p21 * LOG2E;
        Wh1s[row0]     = p10 * LOG2E;  Wh2s[row0]     = s20;
        Wh1s[row0 + 1] = p11 * LOG2E;  Wh2s[row0 + 1] = s21;
        atomicMax(mxk, fenc(fmaxf(s20, s21)));
    }
}

// ---- kernel 2: fused mask+softmax+PV, j-split 2-way, depth-2 register pipeline ----
__global__ __launch_bounds__(512) void k_gat(const ull* __restrict__ maskP,
                                             const __hip_bfloat16* __restrict__ whT,
                                             const float* __restrict__ Wh1s,
                                             const float* __restrict__ Wh2s,
                                             const uint* __restrict__ mxk,
                                             float* __restrict__ pacc,
                                             float* __restrict__ pls) {
    int tid = threadIdx.x;
    int w   = tid >> 6;        // wave 0..7
    int l   = tid & 63;
    int lr  = l & 15;
    int grp = l >> 4;
    int half = blockIdx.x & 1;             // j-half
    int rb   = blockIdx.x >> 1;
    int ib   = rb * 16;
    int row  = ib + lr;

    float wh1s = Wh1s[row];
    float t0 = wh1s + fdec(*mxk);
    float mcs = fmaxf(t0, ALPHA_ * t0);

    f32x4 acc0 = {0.f, 0.f, 0.f, 0.f};
    f32x4 acc1 = acc0, acc2 = acc0, acc3 = acc0, acc4 = acc0;
    s16x8 bones;
    #pragma unroll
    for (int e = 0; e < 8; ++e) bones[e] = (short)0x3F80;   // bf16 1.0

    const __hip_bfloat16* bp = whT + (size_t)lr * NN;
    const ull* mbase = maskP + (size_t)rb * 2048 + (size_t)lr * 4;
    int w0g = w * 32 + grp * 8;
    int shamt = 8 * w + 2 * grp;

#define LOADS(IT, M01, M23, W20, W21, B0, B1, B2, B3) {        \
    int cc = half * 16 + (IT);                                 \
    const ull* mp = mbase + (size_t)cc * 64;                   \
    M01 = *(const ullx2*)(mp);                                 \
    M23 = *(const ullx2*)(mp + 2);                             \
    int jl = cc * 256 + w0g;                                   \
    W20 = *(const f32x4*)(Wh2s + jl);                          \
    W21 = *(const f32x4*)(Wh2s + jl + 4);                      \
    B0  = *(const s16x8*)(bp + jl);                            \
    B1  = *(const s16x8*)(bp + (size_t)16 * NN + jl);          \
    B2  = *(const s16x8*)(bp + (size_t)32 * NN + jl);          \
    B3  = *(const s16x8*)(bp + (size_t)48 * NN + jl); }

#define COMPUTE(M01, M23, W20, W21, B0, B1, B2, B3) {          \
    uint s0 = (uint)(M01[0] >> shamt);                         \
    uint s1 = (uint)(M01[1] >> shamt);                         \
    uint s2 = (uint)(M23[0] >> shamt);                         \
    uint s3 = (uint)(M23[1] >> shamt);                         \
    s16x8 af;                                                  \
    _Pragma("unroll")                                          \
    for (int e = 0; e < 8; ++e) {                              \
        float t = wh1s + ((e < 4) ? W20[e & 3] : W21[e & 3]);  \
        float x = fmaxf(t, ALPHA_ * t);                        \
        float p = exp2f(x - mcs);                              \
        uint sb = (e & 3) == 0 ? s0 : (e & 3) == 1 ? s1 : (e & 3) == 2 ? s2 : s3; \
        p = (sb & (1u << (e >> 2))) ? p : 0.f;                 \
        af[e] = f2bf(p);                                       \
    }                                                          \
    acc0 = __builtin_amdgcn_mfma_f32_16x16x32_bf16(af, B0, acc0, 0, 0, 0); \
    acc1 = __builtin_amdgcn_mfma_f32_16x16x32_bf16(af, B1, acc1, 0, 0, 0); \
    acc2 = __builtin_amdgcn_mfma_f32_16x16x32_bf16(af, B2, acc2, 0, 0, 0); \
    acc3 = __builtin_amdgcn_mfma_f32_16x16x32_bf16(af, B3, acc3, 0, 0, 0); \
    acc4 = __builtin_amdgcn_mfma_f32_16x16x32_bf16(af, bones, acc4, 0, 0, 0); }

    ullx2 am01, am23, bm01, bm23;
    f32x4 aw20, aw21, bw20, bw21;
    s16x8 ab0, ab1, ab2, ab3, bb0, bb1, bb2, bb3;

    LOADS(0, am01, am23, aw20, aw21, ab0, ab1, ab2, ab3)
    LOADS(1, bm01, bm23, bw20, bw21, bb0, bb1, bb2, bb3)

    #pragma unroll
    for (int base = 0; base < 16; base += 2) {
        COMPUTE(am01, am23, aw20, aw21, ab0, ab1, ab2, ab3)
        if (base + 2 < 16) LOADS(base + 2, am01, am23, aw20, aw21, ab0, ab1, ab2, ab3)
        COMPUTE(bm01, bm23, bw20, bw21, bb0, bb1, bb2, bb3)
        if (base + 3 < 16) LOADS(base + 3, bm01, bm23, bw20, bw21, bb0, bb1, bb2, bb3)
    }
#undef LOADS
#undef COMPUTE

    // cross-wave combine via LDS -> per-half partials
    __shared__ float lacc[8][16][65];
    __shared__ float lls[8][16];
    #pragma unroll
    for (int reg = 0; reg < 4; ++reg) {
        int rr = grp * 4 + reg;            // C layout: row=(lane>>4)*4+reg, col=lane&15
        lacc[w][rr][lr]      = acc0[reg];
        lacc[w][rr][16 + lr] = acc1[reg];
        lacc[w][rr][32 + lr] = acc2[reg];
        lacc[w][rr][48 + lr] = acc3[reg];
    }
    if (lr == 0) {
        #pragma unroll
        for (int reg = 0; reg < 4; ++reg) lls[w][grp * 4 + reg] = acc4[reg];
    }
    __syncthreads();

    #pragma unroll
    for (int t = 0; t < 2; ++t) {
        int idx = tid + t * 512;           // 1024 outputs: 16 rows x 64 cols
        int rr = idx >> 6, c = idx & 63;
        float v = 0.f, ls = 0.f;
        #pragma unroll
        for (int ww = 0; ww < 8; ++ww) {
            v += lacc[ww][rr][c];
            ls += lls[ww][rr];
        }
        pacc[((size_t)half * NN + ib + rr) * OUTD + c] = v;
        if (c == 0) pls[half * NN + ib + rr] = ls;
    }
}

// ---- kernel 3: combine the two j-halves, normalize, elu ----
__global__ __launch_bounds__(256) void k_fin(const float* __restrict__ pacc,
                                             const float* __restrict__ pls,
                                             float* __restrict__ out) {
    int idx = blockIdx.x * 256 + threadIdx.x;   // 8192*64
    int row = idx >> 6;
    float v  = pacc[idx] + pacc[(size_t)NN * OUTD + idx];
    float ls = pls[row] + pls[NN + row];
    float hv = v / ls;
    out[idx] = hv > 0.f ? hv : exp2f(hv * LOG2E) - 1.f;
}

extern "C" void kernel_launch(void* const* d_in, const int* in_sizes, int n_in,
                              void* d_out, int out_size, void* d_ws, size_t ws_size,
                              hipStream_t stream) {
    const float* h   = (const float*)d_in[0];
    const int*   adj = (const int*)d_in[1];
    const float* W   = (const float*)d_in[2];
    const float* a   = (const float*)d_in[3];
    float* out = (float*)d_out;

    char* ws = (char*)d_ws;
    ull*             maskP = (ull*)ws;                               // 8 MB
    __hip_bfloat16*  whT   = (__hip_bfloat16*)(ws + 8388608);        // 1 MB
    float*           Wh1s  = (float*)(ws + 8388608 + 1048576);       // 32 KB
    float*           Wh2s  = Wh1s + NN;                              // 32 KB
    uint*            mxk   = (uint*)(Wh2s + NN);                     // 4 B
    float*           pacc  = (float*)(ws + 8388608 + 1048576 + 65536 + 256);  // 4 MB
    float*           pls   = pacc + 2 * NN * OUTD;                   // 64 KB

    hipMemsetAsync(mxk, 0, 4, stream);     // encoded -inf identity
    k_pack<<<NN / 4, 256, 0, stream>>>(adj, maskP);
    k_wh<<<NN / 8, 256, 0, stream>>>(h, W, a, whT, Wh1s, Wh2s, mxk);
    k_gat<<<NN / 8, 512, 0, stream>>>(maskP, whT, Wh1s, Wh2s, mxk, pacc, pls);
    k_fin<<<NN * OUTD / 256, 256, 0, stream>>>(pacc, pls, out);
}